// Round 3
// baseline (1504.796 us; speedup 1.0000x reference)
//
#include <hip/hip_runtime.h>
#include <hip/hip_bf16.h>

// ---------------- runtime dtype helpers ----------------
__device__ __forceinline__ float read_f(const void* p, long long i, int fp32m) {
  return fp32m ? ((const float*)p)[i] : (float)((const __hip_bfloat16*)p)[i];
}

// flags[0] = 1 if external floats are f32 (else bf16); flags[1] = 1 if edge_index is int64
__global__ void detect_k(const void* __restrict__ x, const void* __restrict__ ei,
                         int* __restrict__ flags) {
  const int lane = threadIdx.x;  // 64 threads
  const unsigned short w = ((const unsigned short*)x)[lane * 2];
  const int ef = (w >> 7) & 0xff;
  const bool bf_ok = (ef >= 90 && ef <= 140);          // bf16(N(0,1)) exponent band
  const unsigned hi = ((const unsigned*)ei)[lane * 2 + 1];
  const unsigned long long bm = __ballot(bf_ok);
  const unsigned long long zm = __ballot(hi == 0u);
  if (lane == 0) {
    flags[0] = (bm == ~0ull) ? 0 : 1;
    flags[1] = (zm == ~0ull) ? 1 : 0;
  }
}

// ---------------- canonicalize params ----------------
__global__ void conv_bf16_k(const void* __restrict__ src, __hip_bfloat16* __restrict__ dst,
                            int n, const int* __restrict__ flags) {
  const int i = blockIdx.x * 256 + threadIdx.x;
  if (i < n) dst[i] = __float2bfloat16(read_f(src, i, flags[0]));
}
__global__ void conv_f32_k(const void* __restrict__ src, float* __restrict__ dst,
                           int n, const int* __restrict__ flags) {
  const int i = blockIdx.x * 256 + threadIdx.x;
  if (i < n) dst[i] = read_f(src, i, flags[0]);
}
__global__ void zero_k(float* __restrict__ p, int n) {
  const int i = blockIdx.x * 256 + threadIdx.x;
  if (i < n) p[i] = 0.f;
}

// ---------------- GEMM: out[r, NOUT] = A[r, K] @ W[K, NOUT], bf16 out ----------------
// block = NOUT threads, 8 rows/block. a_mode: 1 = A is bf16, 2 = use flags[0].
template<int K, int NOUT>
__global__ __launch_bounds__(256) void gemm_k(const void* __restrict__ A,
                                              const __hip_bfloat16* __restrict__ W,
                                              __hip_bfloat16* __restrict__ outp,
                                              int nrows, int a_mode, const int* __restrict__ flags) {
  __shared__ float xs[8][K];
  const int fp32m = (a_mode == 2) ? flags[0] : 0;
  const int t = threadIdx.x, base = blockIdx.x * 8;
  for (int i = t; i < 8 * K; i += NOUT) {
    const int m = i / K, k = i - m * K, r = base + m;
    xs[m][k] = (r < nrows) ? read_f(A, (long long)r * K + k, fp32m) : 0.f;
  }
  __syncthreads();
  float acc[8] = {0.f, 0.f, 0.f, 0.f, 0.f, 0.f, 0.f, 0.f};
  for (int k = 0; k < K; k += 4) {
    const float w0 = (float)W[(k + 0) * NOUT + t];
    const float w1 = (float)W[(k + 1) * NOUT + t];
    const float w2 = (float)W[(k + 2) * NOUT + t];
    const float w3 = (float)W[(k + 3) * NOUT + t];
#pragma unroll
    for (int m = 0; m < 8; ++m) {
      const float4 xv = *(const float4*)&xs[m][k];
      acc[m] = fmaf(xv.x, w0, acc[m]);
      acc[m] = fmaf(xv.y, w1, acc[m]);
      acc[m] = fmaf(xv.z, w2, acc[m]);
      acc[m] = fmaf(xv.w, w3, acc[m]);
    }
  }
#pragma unroll
  for (int m = 0; m < 8; ++m) {
    const int r = base + m;
    if (r < nrows) outp[(size_t)r * NOUT + t] = __float2bfloat16(acc[m]);
  }
}

// ---------------- alpha dot products: one wave per node ----------------
__global__ __launch_bounds__(256) void alpha_kk(const __hip_bfloat16* __restrict__ xw,
                                                const float* __restrict__ asrc,
                                                const float* __restrict__ adst,
                                                float* __restrict__ as_, float* __restrict__ ad_,
                                                int n, int F) {
  const int gid = blockIdx.x * 256 + threadIdx.x;
  const int node = gid >> 6, lane = gid & 63;
  if (node >= n) return;
  float s1 = 0.f, s2 = 0.f;
  for (int j = lane; j < F; j += 64) {
    const float v = (float)xw[(size_t)node * F + j];
    s1 += v * asrc[j];
    s2 += v * adst[j];
  }
  for (int off = 32; off; off >>= 1) {
    s1 += __shfl_down(s1, off);
    s2 += __shfl_down(s2, off);
  }
  if (lane == 0) { as_[node] = s1; ad_[node] = s2; }
}

// ---------------- edge helpers ----------------
__device__ __forceinline__ void edge_sd(const void* ei, int e, int E, int EN, int i64m, int n,
                                        int& s, int& d) {
  if (e < E) {
    if (i64m) { s = (int)((const long long*)ei)[e]; d = (int)((const long long*)ei)[E + e]; }
    else      { s = ((const int*)ei)[e];            d = ((const int*)ei)[E + e]; }
  } else { s = d = e - E; }
  s = min(max(s, 0), n - 1);
  d = min(max(d, 0), n - 1);
}
__device__ __forceinline__ float edge_v(const float* as_, const float* ad_, int s, int d) {
  float v = as_[s] + ad_[d];
  v = (v >= 0.f) ? v : 0.2f * v;
  return fminf(v, 60.f);
}

__global__ __launch_bounds__(256) void edge_denom_k(const void* __restrict__ ei,
                                                    const float* __restrict__ as_,
                                                    const float* __restrict__ ad_,
                                                    float* __restrict__ dn, int E, int EN, int n,
                                                    const int* __restrict__ flags) {
  const int e = blockIdx.x * 256 + threadIdx.x;
  if (e >= EN) return;
  int s, d;
  edge_sd(ei, e, E, EN, flags[1], n, s, d);
  atomicAdd(dn + d, expf(edge_v(as_, ad_, s, d)));
}

// one wave per edge; gathers xw[s, col0:col0+ncols], atomics into accum[d, 0:ncols]
__global__ __launch_bounds__(256) void edge_agg_k(const void* __restrict__ ei,
                                                  const float* __restrict__ as_,
                                                  const float* __restrict__ ad_,
                                                  const float* __restrict__ dn,
                                                  const __hip_bfloat16* __restrict__ xw,
                                                  int xw_stride, int col0,
                                                  float* __restrict__ accum, int acc_stride,
                                                  int ncols, int E, int EN, int n,
                                                  const int* __restrict__ flags) {
  const long long gid = (long long)blockIdx.x * 256 + threadIdx.x;
  const int e = (int)(gid >> 6), lane = (int)(gid & 63);
  if (e >= EN) return;
  int s, d;
  edge_sd(ei, e, E, EN, flags[1], n, s, d);
  const float att = expf(edge_v(as_, ad_, s, d)) / fmaxf(dn[d], 1e-30f);
  const __hip_bfloat16* srow = xw + (size_t)s * xw_stride + col0;
  float* drow = accum + (size_t)d * acc_stride;
  for (int j = lane; j < ncols; j += 64)
    atomicAdd(drow + j, att * (float)srow[j]);
}

// ---------------- epilogues ----------------
// accum is N x 128 (compact); h is N x 256 bf16, write columns [col0, col0+128)
__global__ __launch_bounds__(256) void bias_relu_half_k(const float* __restrict__ accum,
                                                        const float* __restrict__ b,
                                                        __hip_bfloat16* __restrict__ h,
                                                        int col0, int total) {
  const int i = blockIdx.x * 256 + threadIdx.x;
  if (i >= total) return;
  const int row = i >> 7, col = i & 127;
  const float v = accum[i] + b[col0 + col];
  h[(size_t)row * 256 + col0 + col] = __float2bfloat16(v > 0.f ? v : 0.f);
}

__global__ __launch_bounds__(256) void bias_out_k(const float* __restrict__ accum,
                                                  const float* __restrict__ b,
                                                  void* __restrict__ outp, int total,
                                                  const int* __restrict__ flags) {
  const int i = blockIdx.x * 256 + threadIdx.x;
  if (i >= total) return;
  const float v = accum[i] + b[i & 127];
  if (flags[0]) ((float*)outp)[i] = v;
  else          ((__hip_bfloat16*)outp)[i] = __float2bfloat16(v);
}

extern "C" void kernel_launch(void* const* d_in, const int* in_sizes, int n_in,
                              void* d_out, int out_size, void* d_ws, size_t ws_size,
                              hipStream_t stream) {
  const void* x   = d_in[0];
  const void* ei  = d_in[1];
  const void* W1  = d_in[2];
  const void* a1s = d_in[3];
  const void* a1d = d_in[4];
  const void* b1  = d_in[5];
  const void* W2  = d_in[6];
  const void* a2s = d_in[7];
  const void* a2d = d_in[8];
  const void* b2  = d_in[9];

  const int N  = in_sizes[0] / 128;   // 50000
  const int E  = in_sizes[1] / 2;     // 800000
  const int EN = E + N;

  // ---- workspace layout (~51.9 MB peak) ----
  // B1: N*256 bf16 (xw1, then h in-place; layer2: reused as f32 accum2 N*128)
  // B2: N*128 f32  (layer1 accum halves; layer2: low half = xw2 bf16 N*128)
  float* W0 = (float*)d_ws;
  __hip_bfloat16* B1 = (__hip_bfloat16*)W0;                 // N*128 f32-words
  float* B2   = W0 + (size_t)N * 128;                       // N*128 f32
  float* as_  = B2 + (size_t)N * 128;
  float* ad_  = as_ + N;
  float* dn   = ad_ + N;
  __hip_bfloat16* W1b = (__hip_bfloat16*)(dn + N);          // 128*256
  __hip_bfloat16* W2b = W1b + 128 * 256;                    // 256*128
  float* vecs = (float*)(W2b + 256 * 128);                  // 1152 f32
  int*   flags = (int*)(vecs + 1152);
  float* v_a1s = vecs, *v_a1d = vecs + 256, *v_b1 = vecs + 512;
  float* v_a2s = vecs + 768, *v_a2d = vecs + 896, *v_b2 = vecs + 1024;

  const int GB = (N + 7) / 8;
  const int NB = (N * 64 + 255) / 256;
  const int EB = (EN + 255) / 256;
  const int AB = (int)(((long long)EN * 64 + 255) / 256);
  const int HB = (N * 128 + 255) / 256;

  // ---- detect dtypes, canonicalize params ----
  detect_k<<<1, 64, 0, stream>>>(x, ei, flags);
  conv_bf16_k<<<(128 * 256 + 255) / 256, 256, 0, stream>>>(W1, W1b, 128 * 256, flags);
  conv_bf16_k<<<(256 * 128 + 255) / 256, 256, 0, stream>>>(W2, W2b, 256 * 128, flags);
  conv_f32_k<<<1, 256, 0, stream>>>(a1s, v_a1s, 256, flags);
  conv_f32_k<<<1, 256, 0, stream>>>(a1d, v_a1d, 256, flags);
  conv_f32_k<<<1, 256, 0, stream>>>(b1,  v_b1,  256, flags);
  conv_f32_k<<<1, 128, 0, stream>>>(a2s, v_a2s, 128, flags);
  conv_f32_k<<<1, 128, 0, stream>>>(a2d, v_a2d, 128, flags);
  conv_f32_k<<<1, 128, 0, stream>>>(b2,  v_b2,  128, flags);

  // ===== layer 1: Fin=128 -> H=256 =====
  gemm_k<128, 256><<<GB, 256, 0, stream>>>(x, W1b, B1, N, /*a_mode=*/2, flags);
  alpha_kk<<<NB, 256, 0, stream>>>(B1, v_a1s, v_a1d, as_, ad_, N, 256);
  zero_k<<<(N + 255) / 256, 256, 0, stream>>>(dn, N);
  edge_denom_k<<<EB, 256, 0, stream>>>(ei, as_, ad_, dn, E, EN, N, flags);
  // half 0: columns [0,128)
  zero_k<<<HB, 256, 0, stream>>>(B2, N * 128);
  edge_agg_k<<<AB, 256, 0, stream>>>(ei, as_, ad_, dn, B1, 256, 0, B2, 128, 128, E, EN, N, flags);
  bias_relu_half_k<<<HB, 256, 0, stream>>>(B2, v_b1, B1, 0, N * 128);
  // half 1: columns [128,256)
  zero_k<<<HB, 256, 0, stream>>>(B2, N * 128);
  edge_agg_k<<<AB, 256, 0, stream>>>(ei, as_, ad_, dn, B1, 256, 128, B2, 128, 128, E, EN, N, flags);
  bias_relu_half_k<<<HB, 256, 0, stream>>>(B2, v_b1, B1, 128, N * 128);
  // B1 now holds h (N x 256 bf16)

  // ===== layer 2: H=256 -> Fout=128 =====
  __hip_bfloat16* xw2 = (__hip_bfloat16*)B2;   // N*128 bf16 in B2's low half
  gemm_k<256, 128><<<GB, 128, 0, stream>>>(B1, W2b, xw2, N, /*a_mode=*/1, flags);
  alpha_kk<<<NB, 256, 0, stream>>>(xw2, v_a2s, v_a2d, as_, ad_, N, 128);
  zero_k<<<(N + 255) / 256, 256, 0, stream>>>(dn, N);
  edge_denom_k<<<EB, 256, 0, stream>>>(ei, as_, ad_, dn, E, EN, N, flags);
  float* acc2 = (float*)B1;                    // h consumed; reuse as f32 accum N*128
  zero_k<<<HB, 256, 0, stream>>>(acc2, N * 128);
  edge_agg_k<<<AB, 256, 0, stream>>>(ei, as_, ad_, dn, xw2, 128, 0, acc2, 128, 128, E, EN, N, flags);
  bias_out_k<<<HB, 256, 0, stream>>>(acc2, v_b2, d_out, N * 128, flags);
}

// Round 4
// 581.159 us; speedup vs baseline: 2.5893x; 2.5893x over previous
//
#include <hip/hip_runtime.h>
#include <hip/hip_bf16.h>

// ---------------- runtime dtype helpers ----------------
__device__ __forceinline__ float read_f(const void* p, long long i, int fp32m) {
  return fp32m ? ((const float*)p)[i] : (float)((const __hip_bfloat16*)p)[i];
}
__device__ __forceinline__ float bf2f(unsigned short u) {
  return __uint_as_float((unsigned)u << 16);
}

// flags[0] = 1 if external floats are f32 (else bf16); flags[1] = 1 if edge_index is int64
__global__ void detect_k(const void* __restrict__ x, const void* __restrict__ ei,
                         int* __restrict__ flags) {
  const int lane = threadIdx.x;  // 64 threads
  const unsigned short w = ((const unsigned short*)x)[lane * 2];
  const int ef = (w >> 7) & 0xff;
  const bool bf_ok = (ef >= 90 && ef <= 140);          // bf16(N(0,1)) exponent band
  const unsigned hi = ((const unsigned*)ei)[lane * 2 + 1];
  const unsigned long long bm = __ballot(bf_ok);
  const unsigned long long zm = __ballot(hi == 0u);
  if (lane == 0) {
    flags[0] = (bm == ~0ull) ? 0 : 1;
    flags[1] = (zm == ~0ull) ? 1 : 0;
  }
}

// ---------------- canonicalize params ----------------
__global__ void conv_bf16_k(const void* __restrict__ src, __hip_bfloat16* __restrict__ dst,
                            int n, const int* __restrict__ flags) {
  const int i = blockIdx.x * 256 + threadIdx.x;
  if (i < n) dst[i] = __float2bfloat16(read_f(src, i, flags[0]));
}
__global__ void conv_f32_k(const void* __restrict__ src, float* __restrict__ dst,
                           int n, const int* __restrict__ flags) {
  const int i = blockIdx.x * 256 + threadIdx.x;
  if (i < n) dst[i] = read_f(src, i, flags[0]);
}
__global__ void zero_int_k(int* __restrict__ p, int n) {
  const int i = blockIdx.x * 256 + threadIdx.x;
  if (i < n) p[i] = 0;
}

// ---------------- edge decode ----------------
__device__ __forceinline__ void edge_sd(const void* ei, int e, int E, int i64m, int n,
                                        int& s, int& d) {
  if (e < E) {
    if (i64m) { s = (int)((const long long*)ei)[e]; d = (int)((const long long*)ei)[E + e]; }
    else      { s = ((const int*)ei)[e];            d = ((const int*)ei)[E + e]; }
  } else { s = d = e - E; }  // self loop
  s = min(max(s, 0), n - 1);
  d = min(max(d, 0), n - 1);
}

// ---------------- CSR build ----------------
__global__ __launch_bounds__(256) void count_k(const void* __restrict__ ei, int* __restrict__ deg,
                                               int E, int EN, int n, const int* __restrict__ flags) {
  const int e = blockIdx.x * 256 + threadIdx.x;
  if (e >= EN) return;
  int s, d;
  edge_sd(ei, e, E, flags[1], n, s, d);
  atomicAdd(deg + d, 1);
}

// single-block inclusive scan: row_ptr[i+1] = sum(deg[0..i]), cursor[i] = row_ptr[i]
__global__ __launch_bounds__(1024) void scan_k(const int* __restrict__ deg,
                                               int* __restrict__ row_ptr,
                                               int* __restrict__ cursor, int n) {
  __shared__ int sdata[1024];
  __shared__ int carry_s;
  if (threadIdx.x == 0) { carry_s = 0; row_ptr[0] = 0; }
  __syncthreads();
  for (int base = 0; base < n; base += 1024) {
    const int i = base + threadIdx.x;
    const int v = (i < n) ? deg[i] : 0;
    sdata[threadIdx.x] = v;
    __syncthreads();
    for (int off = 1; off < 1024; off <<= 1) {
      const int t = (threadIdx.x >= off) ? sdata[threadIdx.x - off] : 0;
      __syncthreads();
      sdata[threadIdx.x] += t;
      __syncthreads();
    }
    const int inc = sdata[threadIdx.x] + carry_s;
    if (i < n) { row_ptr[i + 1] = inc; cursor[i] = inc - v; }
    __syncthreads();
    if (threadIdx.x == 1023) carry_s = inc;
    __syncthreads();
  }
}

__global__ __launch_bounds__(256) void scatter_k(const void* __restrict__ ei, int* __restrict__ cursor,
                                                 int* __restrict__ csr_src,
                                                 int E, int EN, int n, const int* __restrict__ flags) {
  const int e = blockIdx.x * 256 + threadIdx.x;
  if (e >= EN) return;
  int s, d;
  edge_sd(ei, e, E, flags[1], n, s, d);
  const int pos = atomicAdd(cursor + d, 1);
  csr_src[pos] = s;
}

// ---------------- GEMM: out[r, NOUT] = A[r, K] @ W[K, NOUT], bf16 out ----------------
template<int K, int NOUT>
__global__ __launch_bounds__(256) void gemm_k(const void* __restrict__ A,
                                              const __hip_bfloat16* __restrict__ W,
                                              __hip_bfloat16* __restrict__ outp,
                                              int nrows, int a_mode, const int* __restrict__ flags) {
  __shared__ float xs[8][K];
  const int fp32m = (a_mode == 2) ? flags[0] : 0;
  const int t = threadIdx.x, base = blockIdx.x * 8;
  for (int i = t; i < 8 * K; i += NOUT) {
    const int m = i / K, k = i - m * K, r = base + m;
    xs[m][k] = (r < nrows) ? read_f(A, (long long)r * K + k, fp32m) : 0.f;
  }
  __syncthreads();
  float acc[8] = {0.f, 0.f, 0.f, 0.f, 0.f, 0.f, 0.f, 0.f};
  for (int k = 0; k < K; k += 4) {
    const float w0 = (float)W[(k + 0) * NOUT + t];
    const float w1 = (float)W[(k + 1) * NOUT + t];
    const float w2 = (float)W[(k + 2) * NOUT + t];
    const float w3 = (float)W[(k + 3) * NOUT + t];
#pragma unroll
    for (int m = 0; m < 8; ++m) {
      const float4 xv = *(const float4*)&xs[m][k];
      acc[m] = fmaf(xv.x, w0, acc[m]);
      acc[m] = fmaf(xv.y, w1, acc[m]);
      acc[m] = fmaf(xv.z, w2, acc[m]);
      acc[m] = fmaf(xv.w, w3, acc[m]);
    }
  }
#pragma unroll
  for (int m = 0; m < 8; ++m) {
    const int r = base + m;
    if (r < nrows) outp[(size_t)r * NOUT + t] = __float2bfloat16(acc[m]);
  }
}

// ---------------- alpha dot products: one wave per node ----------------
__global__ __launch_bounds__(256) void alpha_kk(const __hip_bfloat16* __restrict__ xw,
                                                const float* __restrict__ asrc,
                                                const float* __restrict__ adst,
                                                float* __restrict__ as_, float* __restrict__ ad_,
                                                int n, int F) {
  const int gid = blockIdx.x * 256 + threadIdx.x;
  const int node = gid >> 6, lane = gid & 63;
  if (node >= n) return;
  float s1 = 0.f, s2 = 0.f;
  for (int j = lane; j < F; j += 64) {
    const float v = (float)xw[(size_t)node * F + j];
    s1 += v * asrc[j];
    s2 += v * adst[j];
  }
  for (int off = 32; off; off >>= 1) {
    s1 += __shfl_down(s1, off);
    s2 += __shfl_down(s2, off);
  }
  if (lane == 0) { as_[node] = s1; ad_[node] = s2; }
}

// ---------------- fused CSR aggregation: one wave per dst node ----------------
// out[d] = (sum_e w_e * xw[src_e]) / (sum_e w_e) + bias; HIDDEN: relu -> bf16 h.
// Final (!HIDDEN): store per flags[0] dtype.
template<int F, bool HIDDEN>
__global__ __launch_bounds__(256) void agg_csr_k(const int* __restrict__ row_ptr,
                                                 const int* __restrict__ csr_src,
                                                 const float* __restrict__ as_,
                                                 const float* __restrict__ ad_,
                                                 const __hip_bfloat16* __restrict__ xw,
                                                 const float* __restrict__ bias,
                                                 void* __restrict__ outp, int n,
                                                 const int* __restrict__ flags) {
  const int gid = blockIdx.x * 256 + threadIdx.x;
  const int node = gid >> 6, lane = gid & 63;
  if (node >= n) return;
  const int start = row_ptr[node], end = row_ptr[node + 1];
  const float adv = ad_[node];
  constexpr int VC = F / 64;
  float acc[VC];
#pragma unroll
  for (int c = 0; c < VC; ++c) acc[c] = 0.f;
  float dsum = 0.f;

  for (int base = start; base < end; base += 64) {
    const int idx = base + lane;
    int s_pre = 0;
    float w_pre = 0.f;
    if (idx < end) {
      s_pre = csr_src[idx];
      float v = as_[s_pre] + adv;
      v = (v >= 0.f) ? v : 0.2f * v;
      w_pre = __expf(fminf(v, 60.f));
    }
    dsum += w_pre;
    const int cnt = min(64, end - base);
    for (int j = 0; j < cnt; ++j) {
      const int s = __shfl(s_pre, j);
      const float w = __shfl(w_pre, j);
      const unsigned short* row = (const unsigned short*)(xw + (size_t)s * F) + lane * VC;
      if (VC == 4) {
        const ushort4 q = *(const ushort4*)row;
        acc[0] = fmaf(w, bf2f(q.x), acc[0]);
        acc[1] = fmaf(w, bf2f(q.y), acc[1]);
        acc[2] = fmaf(w, bf2f(q.z), acc[2]);
        acc[3] = fmaf(w, bf2f(q.w), acc[3]);
      } else {
        const ushort2 q = *(const ushort2*)row;
        acc[0] = fmaf(w, bf2f(q.x), acc[0]);
        acc[1] = fmaf(w, bf2f(q.y), acc[1]);
      }
    }
  }

  for (int off = 32; off; off >>= 1) dsum += __shfl_down(dsum, off);
  dsum = __shfl(dsum, 0);
  const float r = 1.f / fmaxf(dsum, 1e-30f);
  const int col = lane * VC;

  if (HIDDEN) {
    __hip_bfloat16* h = (__hip_bfloat16*)outp + (size_t)node * F + col;
#pragma unroll
    for (int c = 0; c < VC; ++c) {
      const float v = fmaf(acc[c], r, bias[col + c]);
      h[c] = __float2bfloat16(v > 0.f ? v : 0.f);
    }
  } else {
    if (flags[0]) {
      float* o = (float*)outp + (size_t)node * F + col;
#pragma unroll
      for (int c = 0; c < VC; ++c) o[c] = fmaf(acc[c], r, bias[col + c]);
    } else {
      __hip_bfloat16* o = (__hip_bfloat16*)outp + (size_t)node * F + col;
#pragma unroll
      for (int c = 0; c < VC; ++c) o[c] = __float2bfloat16(fmaf(acc[c], r, bias[col + c]));
    }
  }
}

extern "C" void kernel_launch(void* const* d_in, const int* in_sizes, int n_in,
                              void* d_out, int out_size, void* d_ws, size_t ws_size,
                              hipStream_t stream) {
  const void* x   = d_in[0];
  const void* ei  = d_in[1];
  const void* W1  = d_in[2];
  const void* a1s = d_in[3];
  const void* a1d = d_in[4];
  const void* b1  = d_in[5];
  const void* W2  = d_in[6];
  const void* a2s = d_in[7];
  const void* a2d = d_in[8];
  const void* b2  = d_in[9];

  const int N  = in_sizes[0] / 128;   // 50000
  const int E  = in_sizes[1] / 2;     // 800000
  const int EN = E + N;

  // ---- workspace (~56 MB) ----
  __hip_bfloat16* XW1 = (__hip_bfloat16*)d_ws;              // N*256 bf16 (layer2: xw2 N*128)
  __hip_bfloat16* H   = XW1 + (size_t)N * 256;              // N*256 bf16
  float* as_   = (float*)(H + (size_t)N * 256);
  float* ad_   = as_ + N;
  int*   deg   = (int*)(ad_ + N);                           // N
  int*   curs  = deg + N;                                   // N
  int*   rowp  = curs + N;                                  // N+1
  int*   csrc  = rowp + (N + 1);                            // EN
  __hip_bfloat16* W1b = (__hip_bfloat16*)(csrc + EN);       // 128*256
  __hip_bfloat16* W2b = W1b + 128 * 256;                    // 256*128
  float* vecs  = (float*)(W2b + 256 * 128);                 // 1152 f32
  int*   flags = (int*)(vecs + 1152);
  float* v_a1s = vecs,       *v_a1d = vecs + 256, *v_b1 = vecs + 512;
  float* v_a2s = vecs + 768, *v_a2d = vecs + 896, *v_b2 = vecs + 1024;

  const int GB = (N + 7) / 8;
  const int NB = (N * 64 + 255) / 256;       // wave-per-node
  const int EB = (EN + 255) / 256;           // edge-elementwise

  // ---- detect dtypes, canonicalize params ----
  detect_k<<<1, 64, 0, stream>>>(x, ei, flags);
  conv_bf16_k<<<(128 * 256 + 255) / 256, 256, 0, stream>>>(W1, W1b, 128 * 256, flags);
  conv_bf16_k<<<(256 * 128 + 255) / 256, 256, 0, stream>>>(W2, W2b, 256 * 128, flags);
  conv_f32_k<<<1, 256, 0, stream>>>(a1s, v_a1s, 256, flags);
  conv_f32_k<<<1, 256, 0, stream>>>(a1d, v_a1d, 256, flags);
  conv_f32_k<<<1, 256, 0, stream>>>(b1,  v_b1,  256, flags);
  conv_f32_k<<<1, 128, 0, stream>>>(a2s, v_a2s, 128, flags);
  conv_f32_k<<<1, 128, 0, stream>>>(a2d, v_a2d, 128, flags);
  conv_f32_k<<<1, 128, 0, stream>>>(b2,  v_b2,  128, flags);

  // ---- build CSR by destination (once, reused by both layers) ----
  zero_int_k<<<(N + 255) / 256, 256, 0, stream>>>(deg, N);
  count_k<<<EB, 256, 0, stream>>>(ei, deg, E, EN, N, flags);
  scan_k<<<1, 1024, 0, stream>>>(deg, rowp, curs, N);
  scatter_k<<<EB, 256, 0, stream>>>(ei, curs, csrc, E, EN, N, flags);

  // ===== layer 1: Fin=128 -> H=256 =====
  gemm_k<128, 256><<<GB, 256, 0, stream>>>(x, W1b, XW1, N, /*a_mode=*/2, flags);
  alpha_kk<<<NB, 256, 0, stream>>>(XW1, v_a1s, v_a1d, as_, ad_, N, 256);
  agg_csr_k<256, true><<<NB, 256, 0, stream>>>(rowp, csrc, as_, ad_, XW1, v_b1, H, N, flags);

  // ===== layer 2: H=256 -> Fout=128 =====
  __hip_bfloat16* XW2 = XW1;   // reuse (xw1 consumed)
  gemm_k<256, 128><<<GB, 128, 0, stream>>>(H, W2b, XW2, N, /*a_mode=*/1, flags);
  alpha_kk<<<NB, 256, 0, stream>>>(XW2, v_a2s, v_a2d, as_, ad_, N, 128);
  agg_csr_k<128, false><<<NB, 256, 0, stream>>>(rowp, csrc, as_, ad_, XW2, v_b2, d_out, N, flags);
}

// Round 5
// 377.244 us; speedup vs baseline: 3.9889x; 1.5405x over previous
//
#include <hip/hip_runtime.h>
#include <hip/hip_bf16.h>

typedef __attribute__((ext_vector_type(8))) short short8;
typedef __attribute__((ext_vector_type(4))) float floatx4;

// ---------------- runtime dtype helpers ----------------
__device__ __forceinline__ float read_f(const void* p, long long i, int fp32m) {
  return fp32m ? ((const float*)p)[i] : (float)((const __hip_bfloat16*)p)[i];
}
__device__ __forceinline__ float bf2f(unsigned short u) {
  return __uint_as_float((unsigned)u << 16);
}
__device__ __forceinline__ unsigned short f2bf(float f) {   // RNE
  const unsigned u = __float_as_uint(f);
  return (unsigned short)((u + 0x7fffu + ((u >> 16) & 1u)) >> 16);
}

// flags[0] = 1 if external floats are f32 (else bf16); flags[1] = 1 if edge_index is int64
__global__ void detect_k(const void* __restrict__ x, const void* __restrict__ ei,
                         int* __restrict__ flags) {
  const int lane = threadIdx.x;  // 64 threads
  const unsigned short w = ((const unsigned short*)x)[lane * 2];
  const int ef = (w >> 7) & 0xff;
  const bool bf_ok = (ef >= 90 && ef <= 140);
  const unsigned hi = ((const unsigned*)ei)[lane * 2 + 1];
  const unsigned long long bm = __ballot(bf_ok);
  const unsigned long long zm = __ballot(hi == 0u);
  if (lane == 0) {
    flags[0] = (bm == ~0ull) ? 0 : 1;
    flags[1] = (zm == ~0ull) ? 1 : 0;
  }
}

// ---------------- canonicalize params ----------------
__global__ void conv_f32_k(const void* __restrict__ src, float* __restrict__ dst,
                           int n, const int* __restrict__ flags) {
  const int i = blockIdx.x * 256 + threadIdx.x;
  if (i < n) dst[i] = read_f(src, i, flags[0]);
}
__global__ void zero_int_k(int* __restrict__ p, int n) {
  const int i = blockIdx.x * 256 + threadIdx.x;
  if (i < n) p[i] = 0;
}

// pack W[K,NOUT] -> B-fragment order: Wp[((ct*KS+ks)*64 + quad*16+c)*8 + j]
//   = bf16(W[(ks*32+quad*8+j)*NOUT + ct*16+c]),  lane=quad*16+c holds 8 k-values (16B)
template<int K, int NOUT>
__global__ void pack_w_k(const void* __restrict__ W, unsigned short* __restrict__ Wp,
                         const int* __restrict__ flags) {
  const int i = blockIdx.x * 256 + threadIdx.x;
  if (i >= K * NOUT) return;
  const int k = i / NOUT, n = i - k * NOUT;
  const int ct = n >> 4, c = n & 15, ks = k >> 5, quad = (k >> 3) & 3, j = k & 7;
  Wp[(((ct * (K / 32) + ks) * 4 + quad) * 16 + c) * 8 + j] = f2bf(read_f(W, i, flags[0]));
}

// ---------------- edge decode ----------------
__device__ __forceinline__ void edge_sd(const void* ei, int e, int E, int i64m, int n,
                                        int& s, int& d) {
  if (e < E) {
    if (i64m) { s = (int)((const long long*)ei)[e]; d = (int)((const long long*)ei)[E + e]; }
    else      { s = ((const int*)ei)[e];            d = ((const int*)ei)[E + e]; }
  } else { s = d = e - E; }  // self loop
  s = min(max(s, 0), n - 1);
  d = min(max(d, 0), n - 1);
}

// ---------------- CSR build ----------------
__global__ __launch_bounds__(256) void count_k(const void* __restrict__ ei, int* __restrict__ deg,
                                               int E, int EN, int n, const int* __restrict__ flags) {
  const int e = blockIdx.x * 256 + threadIdx.x;
  if (e >= EN) return;
  int s, d;
  edge_sd(ei, e, E, flags[1], n, s, d);
  atomicAdd(deg + d, 1);
}

// hierarchical scan: A) per-block inclusive, B) scan block sums, C) add offsets
__global__ __launch_bounds__(256) void scanA_k(const int* __restrict__ deg, int* __restrict__ rowp,
                                               int* __restrict__ bsum, int n) {
  __shared__ int sd[256];
  const int i = blockIdx.x * 256 + threadIdx.x;
  sd[threadIdx.x] = (i < n) ? deg[i] : 0;
  __syncthreads();
  for (int off = 1; off < 256; off <<= 1) {
    const int t = (threadIdx.x >= off) ? sd[threadIdx.x - off] : 0;
    __syncthreads();
    sd[threadIdx.x] += t;
    __syncthreads();
  }
  if (i < n) rowp[i + 1] = sd[threadIdx.x];
  if (threadIdx.x == 255) bsum[blockIdx.x] = sd[255];
}
__global__ __launch_bounds__(256) void scanB_k(int* __restrict__ bsum, int nb) {
  __shared__ int sd[256];
  sd[threadIdx.x] = (threadIdx.x < nb) ? bsum[threadIdx.x] : 0;
  __syncthreads();
  for (int off = 1; off < 256; off <<= 1) {
    const int t = (threadIdx.x >= off) ? sd[threadIdx.x - off] : 0;
    __syncthreads();
    sd[threadIdx.x] += t;
    __syncthreads();
  }
  if (threadIdx.x < nb) bsum[threadIdx.x] = sd[threadIdx.x];
}
__global__ __launch_bounds__(256) void scanC_k(const int* __restrict__ deg, int* __restrict__ rowp,
                                               int* __restrict__ curs, const int* __restrict__ bsum,
                                               int n) {
  const int i = blockIdx.x * 256 + threadIdx.x;
  if (i >= n) return;
  const int off = (blockIdx.x > 0) ? bsum[blockIdx.x - 1] : 0;
  const int incl = rowp[i + 1] + off;
  rowp[i + 1] = incl;
  curs[i] = incl - deg[i];
  if (i == 0) rowp[0] = 0;
}

__global__ __launch_bounds__(256) void scatter_k(const void* __restrict__ ei, int* __restrict__ cursor,
                                                 int* __restrict__ csr_src,
                                                 int E, int EN, int n, const int* __restrict__ flags) {
  const int e = blockIdx.x * 256 + threadIdx.x;
  if (e >= EN) return;
  int s, d;
  edge_sd(ei, e, E, flags[1], n, s, d);
  const int pos = atomicAdd(cursor + d, 1);
  csr_src[pos] = s;
}

// ---------------- MFMA GEMM + fused alpha ----------------
// out[r, NOUT] = bf16(A[r, K] @ W[K, NOUT]); as_[r] = row.a_src, ad_[r] = row.a_dst.
// One wave per 16-row strip; A-fragments loaded once, looped over NOUT/16 col tiles.
// A layout: A[m=lane&15][k=quad*8+j]; C/D: col=lane&15, row=quad*4+reg (verified gfx950).
template<int K, int NOUT, int AMODE>  // AMODE: 0 = A bf16, 2 = A dtype per flags[0]
__global__ __launch_bounds__(256) void gemm_mfma_k(const void* __restrict__ A,
                                                   const unsigned short* __restrict__ Wp,
                                                   unsigned short* __restrict__ outp,
                                                   const float* __restrict__ av_src,
                                                   const float* __restrict__ av_dst,
                                                   float* __restrict__ as_, float* __restrict__ ad_,
                                                   int nrows, const int* __restrict__ flags) {
  constexpr int KS = K / 32;
  constexpr int CT = NOUT / 16;
  const int wave = threadIdx.x >> 6, lane = threadIdx.x & 63;
  const int quad = lane >> 4, c = lane & 15;
  const int row0 = (blockIdx.x * 4 + wave) * 16;
  if (row0 >= nrows) return;
  int arow = row0 + c;
  if (arow >= nrows) arow = nrows - 1;   // clamp; garbage rows guarded at write
  const int fp32m = (AMODE == 2) ? flags[0] : 0;

  short8 afrag[KS];
  if (fp32m) {
    const float* Ab = (const float*)A + (size_t)arow * K;
#pragma unroll
    for (int ks = 0; ks < KS; ++ks) {
      const float4* p = (const float4*)(Ab + ks * 32 + quad * 8);
      const float4 u = p[0], v = p[1];
      short8 f;
      f[0] = (short)f2bf(u.x); f[1] = (short)f2bf(u.y);
      f[2] = (short)f2bf(u.z); f[3] = (short)f2bf(u.w);
      f[4] = (short)f2bf(v.x); f[5] = (short)f2bf(v.y);
      f[6] = (short)f2bf(v.z); f[7] = (short)f2bf(v.w);
      afrag[ks] = f;
    }
  } else {
    const unsigned short* Ab = (const unsigned short*)A + (size_t)arow * K;
#pragma unroll
    for (int ks = 0; ks < KS; ++ks)
      afrag[ks] = *(const short8*)(Ab + ks * 32 + quad * 8);
  }

  float pa_s[4] = {0.f, 0.f, 0.f, 0.f}, pa_d[4] = {0.f, 0.f, 0.f, 0.f};
#pragma unroll
  for (int ct = 0; ct < CT; ++ct) {
    floatx4 acc = {0.f, 0.f, 0.f, 0.f};
#pragma unroll
    for (int ks = 0; ks < KS; ++ks) {
      const short8 bfrag = *(const short8*)(Wp + (size_t)((ct * KS + ks) * 64 + lane) * 8);
      acc = __builtin_amdgcn_mfma_f32_16x16x32_bf16(afrag[ks], bfrag, acc, 0, 0, 0);
    }
    const float asv = av_src[ct * 16 + c], adv = av_dst[ct * 16 + c];
#pragma unroll
    for (int r = 0; r < 4; ++r) {
      const int rr = row0 + quad * 4 + r;
      pa_s[r] = fmaf(acc[r], asv, pa_s[r]);
      pa_d[r] = fmaf(acc[r], adv, pa_d[r]);
      if (rr < nrows) outp[(size_t)rr * NOUT + ct * 16 + c] = f2bf(acc[r]);
    }
  }
  // reduce alpha partials across the 16 col-lanes (xor flips only c bits)
  for (int off = 1; off < 16; off <<= 1) {
#pragma unroll
    for (int r = 0; r < 4; ++r) {
      pa_s[r] += __shfl_xor(pa_s[r], off);
      pa_d[r] += __shfl_xor(pa_d[r], off);
    }
  }
  if (c == 0) {
#pragma unroll
    for (int r = 0; r < 4; ++r) {
      const int rr = row0 + quad * 4 + r;
      if (rr < nrows) { as_[rr] = pa_s[r]; ad_[rr] = pa_d[r]; }
    }
  }
}

// ---------------- fused CSR aggregation: one wave per dst node ----------------
template<int F, bool HIDDEN>
__global__ __launch_bounds__(256) void agg_csr_k(const int* __restrict__ row_ptr,
                                                 const int* __restrict__ csr_src,
                                                 const float* __restrict__ as_,
                                                 const float* __restrict__ ad_,
                                                 const __hip_bfloat16* __restrict__ xw,
                                                 const float* __restrict__ bias,
                                                 void* __restrict__ outp, int n,
                                                 const int* __restrict__ flags) {
  const int gid = blockIdx.x * 256 + threadIdx.x;
  const int node = gid >> 6, lane = gid & 63;
  if (node >= n) return;
  const int start = row_ptr[node], end = row_ptr[node + 1];
  const float adv = ad_[node];
  constexpr int VC = F / 64;
  float acc[VC];
#pragma unroll
  for (int c = 0; c < VC; ++c) acc[c] = 0.f;
  float dsum = 0.f;

  for (int base = start; base < end; base += 64) {
    const int idx = base + lane;
    int s_pre = 0;
    float w_pre = 0.f;
    if (idx < end) {
      s_pre = csr_src[idx];
      float v = as_[s_pre] + adv;
      v = (v >= 0.f) ? v : 0.2f * v;
      w_pre = __expf(fminf(v, 60.f));
    }
    dsum += w_pre;
    const int cnt = min(64, end - base);
    for (int j = 0; j < cnt; ++j) {
      const int s = __shfl(s_pre, j);
      const float w = __shfl(w_pre, j);
      const unsigned short* row = (const unsigned short*)(xw + (size_t)s * F) + lane * VC;
      if (VC == 4) {
        const ushort4 q = *(const ushort4*)row;
        acc[0] = fmaf(w, bf2f(q.x), acc[0]);
        acc[1] = fmaf(w, bf2f(q.y), acc[1]);
        acc[2] = fmaf(w, bf2f(q.z), acc[2]);
        acc[3] = fmaf(w, bf2f(q.w), acc[3]);
      } else {
        const ushort2 q = *(const ushort2*)row;
        acc[0] = fmaf(w, bf2f(q.x), acc[0]);
        acc[1] = fmaf(w, bf2f(q.y), acc[1]);
      }
    }
  }

  for (int off = 32; off; off >>= 1) dsum += __shfl_down(dsum, off);
  dsum = __shfl(dsum, 0);
  const float r = 1.f / fmaxf(dsum, 1e-30f);
  const int col = lane * VC;

  if (HIDDEN) {
    __hip_bfloat16* h = (__hip_bfloat16*)outp + (size_t)node * F + col;
#pragma unroll
    for (int c = 0; c < VC; ++c) {
      const float v = fmaf(acc[c], r, bias[col + c]);
      h[c] = __float2bfloat16(v > 0.f ? v : 0.f);
    }
  } else {
    if (flags[0]) {
      float* o = (float*)outp + (size_t)node * F + col;
#pragma unroll
      for (int c = 0; c < VC; ++c) o[c] = fmaf(acc[c], r, bias[col + c]);
    } else {
      __hip_bfloat16* o = (__hip_bfloat16*)outp + (size_t)node * F + col;
#pragma unroll
      for (int c = 0; c < VC; ++c) o[c] = __float2bfloat16(fmaf(acc[c], r, bias[col + c]));
    }
  }
}

extern "C" void kernel_launch(void* const* d_in, const int* in_sizes, int n_in,
                              void* d_out, int out_size, void* d_ws, size_t ws_size,
                              hipStream_t stream) {
  const void* x   = d_in[0];
  const void* ei  = d_in[1];
  const void* W1  = d_in[2];
  const void* a1s = d_in[3];
  const void* a1d = d_in[4];
  const void* b1  = d_in[5];
  const void* W2  = d_in[6];
  const void* a2s = d_in[7];
  const void* a2d = d_in[8];
  const void* b2  = d_in[9];

  const int N  = in_sizes[0] / 128;   // 50000
  const int E  = in_sizes[1] / 2;     // 800000
  const int EN = E + N;

  // ---- workspace (~56 MB) ----
  unsigned short* XW1 = (unsigned short*)d_ws;              // N*256 bf16 (layer2: XW2 = low N*128)
  unsigned short* H   = XW1 + (size_t)N * 256;              // N*256 bf16
  float* as_   = (float*)(H + (size_t)N * 256);
  float* ad_   = as_ + N;
  int*   deg   = (int*)(ad_ + N);                           // N
  int*   curs  = deg + N;                                   // N
  int*   rowp  = curs + N;                                  // N+1
  int*   csrc  = rowp + (N + 1);                            // EN
  unsigned short* Wp1 = (unsigned short*)(csrc + EN);       // 128*256
  unsigned short* Wp2 = Wp1 + 128 * 256;                    // 256*128
  float* vecs  = (float*)(Wp2 + 256 * 128);                 // 1152 f32
  int*   flags = (int*)(vecs + 1152);
  int*   bsum  = flags + 4;                                 // 256
  float* v_a1s = vecs,       *v_a1d = vecs + 256, *v_b1 = vecs + 512;
  float* v_a2s = vecs + 768, *v_a2d = vecs + 896, *v_b2 = vecs + 1024;

  const int NB = (N * 64 + 255) / 256;       // wave-per-node blocks
  const int EB = (EN + 255) / 256;           // edge-elementwise blocks
  const int SB = (N + 255) / 256;            // node-elementwise blocks (scan width)
  const int MB = (N + 63) / 64;              // mfma gemm blocks (4 waves x 16 rows)

  // ---- detect dtypes, canonicalize params ----
  detect_k<<<1, 64, 0, stream>>>(x, ei, flags);
  pack_w_k<128, 256><<<(128 * 256 + 255) / 256, 256, 0, stream>>>(W1, Wp1, flags);
  pack_w_k<256, 128><<<(256 * 128 + 255) / 256, 256, 0, stream>>>(W2, Wp2, flags);
  conv_f32_k<<<1, 256, 0, stream>>>(a1s, v_a1s, 256, flags);
  conv_f32_k<<<1, 256, 0, stream>>>(a1d, v_a1d, 256, flags);
  conv_f32_k<<<1, 256, 0, stream>>>(b1,  v_b1,  256, flags);
  conv_f32_k<<<1, 128, 0, stream>>>(a2s, v_a2s, 128, flags);
  conv_f32_k<<<1, 128, 0, stream>>>(a2d, v_a2d, 128, flags);
  conv_f32_k<<<1, 128, 0, stream>>>(b2,  v_b2,  128, flags);

  // ---- build CSR by destination (once, reused by both layers) ----
  zero_int_k<<<SB, 256, 0, stream>>>(deg, N);
  count_k<<<EB, 256, 0, stream>>>(ei, deg, E, EN, N, flags);
  scanA_k<<<SB, 256, 0, stream>>>(deg, rowp, bsum, N);
  scanB_k<<<1, 256, 0, stream>>>(bsum, SB);
  scanC_k<<<SB, 256, 0, stream>>>(deg, rowp, curs, bsum, N);
  scatter_k<<<EB, 256, 0, stream>>>(ei, curs, csrc, E, EN, N, flags);

  // ===== layer 1: Fin=128 -> H=256 =====
  gemm_mfma_k<128, 256, 2><<<MB, 256, 0, stream>>>(x, Wp1, XW1, v_a1s, v_a1d, as_, ad_, N, flags);
  agg_csr_k<256, true><<<NB, 256, 0, stream>>>(rowp, csrc, as_, ad_,
                                               (const __hip_bfloat16*)XW1, v_b1, H, N, flags);

  // ===== layer 2: H=256 -> Fout=128 =====
  unsigned short* XW2 = XW1;   // reuse (xw1 consumed)
  gemm_mfma_k<256, 128, 0><<<MB, 256, 0, stream>>>(H, Wp2, XW2, v_a2s, v_a2d, as_, ad_, N, flags);
  agg_csr_k<128, false><<<NB, 256, 0, stream>>>(rowp, csrc, as_, ad_,
                                                (const __hip_bfloat16*)XW2, v_b2, d_out, N, flags);
}